// Round 4
// baseline (491.122 us; speedup 1.0000x reference)
//
#include <hip/hip_runtime.h>
#include <hip/hip_bf16.h>

// KMeans predict: ids = argmin_k ||c_k||^2 - 2 x.c_k    (N=500000, D=64, K=1024)
// Pass 1: 32x32x16 f16 MFMA, A=centers (from LDS, hi only), B=points (regs,
//         hi+lo split). C-init = -0.5||c||^2 fp32. Per-lane (single point)
//         tournament top-2 with 4-bit reg-id packed into score mantissa.
//         gap < MARGIN -> uncertain list.
// Pass 2: fp64-exact block-per-point recompute for uncertain points.

#define N_PTS 500000
#define DIM   64
#define K_CENT 1024
#define MARGIN 8.0e-3f   // covers c-hi noise (~9e-4 rms) + 4-bit pack quant

typedef _Float16 half8   __attribute__((ext_vector_type(8)));
typedef float    floatx16 __attribute__((ext_vector_type(16)));

// ---------------------------------------------------------------- pass 1 ----
// 512 threads = 8 waves; each wave owns 32 points (one 32-col C tile).
// Centers staged fp16(hi) to LDS in 4 stages of 256, row stride 72 halves
// (144 B — measured 0 bank conflicts in R3). negm2 = -0.5||c||^2 in fp32.
__launch_bounds__(512, 4)
__global__ void kmeans_pass1(const float* __restrict__ x,
                             const float* __restrict__ centers,
                             int* __restrict__ out,
                             int* __restrict__ counter,
                             int* __restrict__ ulist,
                             int capacity)
{
    __shared__ __align__(16) _Float16 ldsC[256 * 72];   // 36.9 KB
    __shared__ float negm2[256];

    const int tid  = threadIdx.x;
    const int lane = tid & 63;
    const int wave = tid >> 6;
    const int col  = lane & 31;      // point within wave's 32
    const int h    = lane >> 5;      // k-half selector (8 of 16 per chunk)

    const int p  = blockIdx.x * 256 + wave * 32 + col;
    const int pc = p > N_PTS - 1 ? N_PTS - 1 : p;       // tail clamp (dup)

    // ---- B fragments (points), hi+lo: B[k = c*16 + h*8 + j][n = col] ----
    half8 bh[4], bl[4];
    {
        const float* xr = x + (size_t)pc * DIM + h * 8;
        #pragma unroll
        for (int c = 0; c < 4; ++c) {
            float4 f0 = *(const float4*)(xr + c * 16);
            float4 f1 = *(const float4*)(xr + c * 16 + 4);
            float v[8] = {f0.x, f0.y, f0.z, f0.w, f1.x, f1.y, f1.z, f1.w};
            half8 hi, lo;
            #pragma unroll
            for (int j = 0; j < 8; ++j) {
                _Float16 hj = (_Float16)v[j];
                hi[j] = hj;
                lo[j] = (_Float16)(v[j] - (float)hj);   // exact residual
            }
            bh[c] = hi; bl[c] = lo;
        }
    }

    float m1 = -3.0e38f, m2 = -3.0e38f;
    int   ctb = 0;

    for (int s = 0; s < 4; ++s) {
        __syncthreads();                                 // prev-stage readers
        // ---- stage 256 centers: thread t -> center t>>1, half t&1 ----
        {
            const int c = tid >> 1, hh = tid & 1;
            const float* src = centers + (size_t)(s * 256 + c) * DIM + hh * 32;
            float ss = 0.f;
            #pragma unroll
            for (int g = 0; g < 4; ++g) {
                float4 f0 = *(const float4*)(src + g * 8);
                float4 f1 = *(const float4*)(src + g * 8 + 4);
                float v[8] = {f0.x, f0.y, f0.z, f0.w, f1.x, f1.y, f1.z, f1.w};
                half8 hi;
                #pragma unroll
                for (int j = 0; j < 8; ++j) {
                    ss = fmaf(v[j], v[j], ss);
                    hi[j] = (_Float16)v[j];
                }
                *(half8*)&ldsC[c * 72 + hh * 32 + g * 8] = hi;
            }
            float oss = __shfl_xor(ss, 1);
            if (hh == 0) negm2[c] = -0.5f * (ss + oss);
        }
        __syncthreads();

        // ---- 8 center-tiles of 32 in this stage ----
        for (int ctl = 0; ctl < 8; ++ctl) {
            const int ct = s * 8 + ctl;
            // C-init: acc[4q+j] holds center row 8q + j + 4h
            const float* nm = &negm2[ctl * 32 + 4 * h];
            float4 q0 = *(const float4*)(nm);
            float4 q1 = *(const float4*)(nm + 8);
            float4 q2 = *(const float4*)(nm + 16);
            float4 q3 = *(const float4*)(nm + 24);
            floatx16 acc;
            acc[0]=q0.x; acc[1]=q0.y; acc[2]=q0.z; acc[3]=q0.w;
            acc[4]=q1.x; acc[5]=q1.y; acc[6]=q1.z; acc[7]=q1.w;
            acc[8]=q2.x; acc[9]=q2.y; acc[10]=q2.z; acc[11]=q2.w;
            acc[12]=q3.x; acc[13]=q3.y; acc[14]=q3.z; acc[15]=q3.w;

            // A fragments (centers): A[m = ctl*32+col][k = c*16 + h*8 + j]
            const _Float16* ap = &ldsC[(ctl * 32 + col) * 72 + h * 8];
            #pragma unroll
            for (int c = 0; c < 4; ++c) {
                half8 a = *(const half8*)(ap + c * 16);
                acc = __builtin_amdgcn_mfma_f32_32x32x16_f16(a, bh[c], acc, 0, 0, 0);
                acc = __builtin_amdgcn_mfma_f32_32x32x16_f16(a, bl[c], acc, 0, 0, 0);
            }

            // ---- tournament top-2 over 16 regs, reg-id packed in low bits ----
            float kk[16];
            #pragma unroll
            for (int i = 0; i < 16; ++i) {
                unsigned u = (__float_as_uint(acc[i]) & 0xFFFFFFF0u) | (unsigned)i;
                kk[i] = __uint_as_float(u);
            }
            float M8[8], S8[8];
            #pragma unroll
            for (int j = 0; j < 8; ++j) {
                M8[j] = fmaxf(kk[2*j], kk[2*j+1]);
                S8[j] = fminf(kk[2*j], kk[2*j+1]);
            }
            float M4[4], S4[4];
            #pragma unroll
            for (int j = 0; j < 4; ++j) {
                M4[j] = fmaxf(M8[2*j], M8[2*j+1]);
                S4[j] = fmaxf(fmaxf(fminf(M8[2*j], M8[2*j+1]), S8[2*j]), S8[2*j+1]);
            }
            float M2a[2], S2a[2];
            #pragma unroll
            for (int j = 0; j < 2; ++j) {
                M2a[j] = fmaxf(M4[2*j], M4[2*j+1]);
                S2a[j] = fmaxf(fmaxf(fminf(M4[2*j], M4[2*j+1]), S4[2*j]), S4[2*j+1]);
            }
            float M16 = fmaxf(M2a[0], M2a[1]);
            float S16 = fmaxf(fmaxf(fminf(M2a[0], M2a[1]), S2a[0]), S2a[1]);

            m2 = fmaxf(fmaxf(m2, S16), fminf(M16, m1));
            bool gt = M16 > m1;
            m1 = gt ? M16 : m1;
            ctb = gt ? ct : ctb;
        }
    }

    // ---- epilogue: recover center id, merge the two k-halves, write ----
    {
        unsigned u = __float_as_uint(m1);
        int reg = (int)(u & 15u);
        int row = (reg & 3) + 8 * (reg >> 2) + 4 * h;
        int cid = ctb * 32 + row;

        float o1 = __shfl_xor(m1, 32);
        float o2 = __shfl_xor(m2, 32);
        int  ocid = __shfl_xor(cid, 32);
        float nm2 = fmaxf(fmaxf(m2, o2), fminf(m1, o1));
        bool take = o1 > m1;
        float nm1 = take ? o1 : m1;
        int  ncid = take ? ocid : cid;

        if (h == 0 && p < N_PTS) {
            out[p] = ncid;
            if (nm1 - nm2 < MARGIN) {                    // too close -> fp64
                int slot = atomicAdd(counter, 1);
                if (slot < capacity) ulist[slot] = p;
            }
        }
    }
}

// ---------------------------------------------------------------- pass 2 ----
// fp64-exact, one point per block-iteration. x row staged once in LDS
// (broadcast reads); each thread scans 4 centers; lexicographic argmin.
__launch_bounds__(256)
__global__ void kmeans_pass2(const float* __restrict__ x,
                             const float* __restrict__ centers,
                             int* __restrict__ out,
                             const int* __restrict__ counter,
                             const int* __restrict__ ulist,
                             int capacity)
{
    __shared__ float xs[64];
    __shared__ double wv[4];
    __shared__ int    wi[4];

    int count = *counter;
    if (count > capacity) count = capacity;
    const int tid  = threadIdx.x;
    const int lane = tid & 63;
    const int wave = tid >> 6;

    for (int u = blockIdx.x; u < count; u += gridDim.x) {
        __syncthreads();                               // protect xs/wv reuse
        const int p = ulist[u];
        if (tid < 16)
            ((float4*)xs)[tid] = ((const float4*)(x + (size_t)p * DIM))[tid];
        __syncthreads();

        double bv = 1.0e300; int bi = 0;
        #pragma unroll
        for (int j = 0; j < 4; ++j) {
            const int c = tid + j * 256;
            const float4* crow = (const float4*)(centers + (size_t)c * DIM);
            double m2s = 0.0, dot = 0.0;
            #pragma unroll
            for (int kc = 0; kc < 16; ++kc) {
                float4 cv = crow[kc];
                float4 xv = *(const float4*)&xs[kc * 4];   // LDS broadcast
                double c0 = cv.x, c1 = cv.y, c2 = cv.z, c3 = cv.w;
                m2s += c0 * c0 + c1 * c1 + c2 * c2 + c3 * c3;
                dot += c0 * (double)xv.x + c1 * (double)xv.y
                     + c2 * (double)xv.z + c3 * (double)xv.w;
            }
            double sc = m2s - 2.0 * dot;
            if (sc < bv || (sc == bv && c < bi)) { bv = sc; bi = c; }
        }
        #pragma unroll
        for (int m = 1; m <= 32; m <<= 1) {
            double ov = __shfl_xor(bv, m);
            int    oi = __shfl_xor(bi, m);
            if (ov < bv || (ov == bv && oi < bi)) { bv = ov; bi = oi; }
        }
        if (lane == 0) { wv[wave] = bv; wi[wave] = bi; }
        __syncthreads();
        if (tid == 0) {
            double v = wv[0]; int i = wi[0];
            #pragma unroll
            for (int w = 1; w < 4; ++w) {
                if (wv[w] < v || (wv[w] == v && wi[w] < i)) { v = wv[w]; i = wi[w]; }
            }
            out[p] = i;
        }
    }
}

extern "C" void kernel_launch(void* const* d_in, const int* in_sizes, int n_in,
                              void* d_out, int out_size, void* d_ws, size_t ws_size,
                              hipStream_t stream)
{
    const float* x       = (const float*)d_in[0];
    const float* centers = (const float*)d_in[1];
    int* out     = (int*)d_out;
    int* counter = (int*)d_ws;
    int* ulist   = (int*)((char*)d_ws + 64);
    int capacity = (int)((ws_size > 64 ? ws_size - 64 : 0) / sizeof(int));
    if (capacity > N_PTS) capacity = N_PTS;

    hipMemsetAsync(d_ws, 0, 64, stream);
    dim3 g1((N_PTS + 255) / 256);     // 1954 blocks x 512 threads, 256 pts each
    kmeans_pass1<<<g1, 512, 0, stream>>>(x, centers, out, counter, ulist, capacity);
    kmeans_pass2<<<1024, 256, 0, stream>>>(x, centers, out, counter, ulist, capacity);
}

// Round 5
// 401.359 us; speedup vs baseline: 1.2236x; 1.2236x over previous
//
#include <hip/hip_runtime.h>
#include <hip/hip_bf16.h>

// KMeans predict: ids = argmin_k ||c_k||^2 - 2 x.c_k    (N=500000, D=64, K=1024)
// Pass 0: precompute fp64 ||c||^2 for all centers (pass2's authority table).
// Pass 1: 32x32x16 f16 MFMA, A=centers (LDS, hi only), B=points (regs, hi+lo).
//         C-init = -0.5||c||^2 fp32. Tournament top-2, 4-bit reg-id packed in
//         mantissa. gap < MARGIN -> uncertain list.  [BIT-IDENTICAL to R4]
// Pass 2: fp64-exact WAVE-per-point rescan (coalesced 4-rows-per-load,
//         butterfly dot-reduce) for uncertain points.

#define N_PTS 500000
#define DIM   64
#define K_CENT 1024
#define MARGIN 8.0e-3f   // covers c-hi noise (~2e-3 rms) + 4-bit pack quant

typedef _Float16 half8   __attribute__((ext_vector_type(8)));
typedef float    floatx16 __attribute__((ext_vector_type(16)));

// ---------------------------------------------------------------- pass 0 ----
// fp64 ||c||^2 table, 1024 centers, one thread each.
__global__ void kmeans_m2pre(const float* __restrict__ centers,
                             double* __restrict__ m2d)
{
    const int c = blockIdx.x * 256 + threadIdx.x;
    if (c >= K_CENT) return;
    const float4* crow = (const float4*)(centers + (size_t)c * DIM);
    double s = 0.0;
    #pragma unroll
    for (int kc = 0; kc < 16; ++kc) {
        float4 v = crow[kc];
        double a = v.x, b = v.y, cc = v.z, d = v.w;
        s += a * a + b * b + cc * cc + d * d;
    }
    m2d[c] = s;
}

// ---------------------------------------------------------------- pass 1 ----
// 512 threads = 8 waves; each wave owns 32 points (one 32-col C tile).
// Centers staged fp16(hi) to LDS in 4 stages of 256, row stride 72 halves
// (144 B — measured 0 bank conflicts). negm2 = -0.5||c||^2 in fp32.
__launch_bounds__(512, 4)
__global__ void kmeans_pass1(const float* __restrict__ x,
                             const float* __restrict__ centers,
                             int* __restrict__ out,
                             int* __restrict__ counter,
                             int* __restrict__ ulist,
                             int capacity)
{
    __shared__ __align__(16) _Float16 ldsC[256 * 72];   // 36.9 KB
    __shared__ float negm2[256];

    const int tid  = threadIdx.x;
    const int lane = tid & 63;
    const int wave = tid >> 6;
    const int col  = lane & 31;      // point within wave's 32
    const int h    = lane >> 5;      // k-half selector (8 of 16 per chunk)

    const int p  = blockIdx.x * 256 + wave * 32 + col;
    const int pc = p > N_PTS - 1 ? N_PTS - 1 : p;       // tail clamp (dup)

    // ---- B fragments (points), hi+lo: B[k = c*16 + h*8 + j][n = col] ----
    half8 bh[4], bl[4];
    {
        const float* xr = x + (size_t)pc * DIM + h * 8;
        #pragma unroll
        for (int c = 0; c < 4; ++c) {
            float4 f0 = *(const float4*)(xr + c * 16);
            float4 f1 = *(const float4*)(xr + c * 16 + 4);
            float v[8] = {f0.x, f0.y, f0.z, f0.w, f1.x, f1.y, f1.z, f1.w};
            half8 hi, lo;
            #pragma unroll
            for (int j = 0; j < 8; ++j) {
                _Float16 hj = (_Float16)v[j];
                hi[j] = hj;
                lo[j] = (_Float16)(v[j] - (float)hj);   // exact residual
            }
            bh[c] = hi; bl[c] = lo;
        }
    }

    float m1 = -3.0e38f, m2 = -3.0e38f;
    int   ctb = 0;

    for (int s = 0; s < 4; ++s) {
        __syncthreads();                                 // prev-stage readers
        // ---- stage 256 centers: thread t -> center t>>1, half t&1 ----
        {
            const int c = tid >> 1, hh = tid & 1;
            const float* src = centers + (size_t)(s * 256 + c) * DIM + hh * 32;
            float ss = 0.f;
            #pragma unroll
            for (int g = 0; g < 4; ++g) {
                float4 f0 = *(const float4*)(src + g * 8);
                float4 f1 = *(const float4*)(src + g * 8 + 4);
                float v[8] = {f0.x, f0.y, f0.z, f0.w, f1.x, f1.y, f1.z, f1.w};
                half8 hi;
                #pragma unroll
                for (int j = 0; j < 8; ++j) {
                    ss = fmaf(v[j], v[j], ss);
                    hi[j] = (_Float16)v[j];
                }
                *(half8*)&ldsC[c * 72 + hh * 32 + g * 8] = hi;
            }
            float oss = __shfl_xor(ss, 1);
            if (hh == 0) negm2[c] = -0.5f * (ss + oss);
        }
        __syncthreads();

        // ---- 8 center-tiles of 32 in this stage ----
        for (int ctl = 0; ctl < 8; ++ctl) {
            const int ct = s * 8 + ctl;
            // C-init: acc[4q+j] holds center row 8q + j + 4h
            const float* nm = &negm2[ctl * 32 + 4 * h];
            float4 q0 = *(const float4*)(nm);
            float4 q1 = *(const float4*)(nm + 8);
            float4 q2 = *(const float4*)(nm + 16);
            float4 q3 = *(const float4*)(nm + 24);
            floatx16 acc;
            acc[0]=q0.x; acc[1]=q0.y; acc[2]=q0.z; acc[3]=q0.w;
            acc[4]=q1.x; acc[5]=q1.y; acc[6]=q1.z; acc[7]=q1.w;
            acc[8]=q2.x; acc[9]=q2.y; acc[10]=q2.z; acc[11]=q2.w;
            acc[12]=q3.x; acc[13]=q3.y; acc[14]=q3.z; acc[15]=q3.w;

            // A fragments (centers): A[m = ctl*32+col][k = c*16 + h*8 + j]
            const _Float16* ap = &ldsC[(ctl * 32 + col) * 72 + h * 8];
            #pragma unroll
            for (int c = 0; c < 4; ++c) {
                half8 a = *(const half8*)(ap + c * 16);
                acc = __builtin_amdgcn_mfma_f32_32x32x16_f16(a, bh[c], acc, 0, 0, 0);
                acc = __builtin_amdgcn_mfma_f32_32x32x16_f16(a, bl[c], acc, 0, 0, 0);
            }

            // ---- tournament top-2 over 16 regs, reg-id packed in low bits ----
            float kk[16];
            #pragma unroll
            for (int i = 0; i < 16; ++i) {
                unsigned u = (__float_as_uint(acc[i]) & 0xFFFFFFF0u) | (unsigned)i;
                kk[i] = __uint_as_float(u);
            }
            float M8[8], S8[8];
            #pragma unroll
            for (int j = 0; j < 8; ++j) {
                M8[j] = fmaxf(kk[2*j], kk[2*j+1]);
                S8[j] = fminf(kk[2*j], kk[2*j+1]);
            }
            float M4[4], S4[4];
            #pragma unroll
            for (int j = 0; j < 4; ++j) {
                M4[j] = fmaxf(M8[2*j], M8[2*j+1]);
                S4[j] = fmaxf(fmaxf(fminf(M8[2*j], M8[2*j+1]), S8[2*j]), S8[2*j+1]);
            }
            float M2a[2], S2a[2];
            #pragma unroll
            for (int j = 0; j < 2; ++j) {
                M2a[j] = fmaxf(M4[2*j], M4[2*j+1]);
                S2a[j] = fmaxf(fmaxf(fminf(M4[2*j], M4[2*j+1]), S4[2*j]), S4[2*j+1]);
            }
            float M16 = fmaxf(M2a[0], M2a[1]);
            float S16 = fmaxf(fmaxf(fminf(M2a[0], M2a[1]), S2a[0]), S2a[1]);

            m2 = fmaxf(fmaxf(m2, S16), fminf(M16, m1));
            bool gt = M16 > m1;
            m1 = gt ? M16 : m1;
            ctb = gt ? ct : ctb;
        }
    }

    // ---- epilogue: recover center id, merge the two k-halves, write ----
    {
        unsigned u = __float_as_uint(m1);
        int reg = (int)(u & 15u);
        int row = (reg & 3) + 8 * (reg >> 2) + 4 * h;
        int cid = ctb * 32 + row;

        float o1 = __shfl_xor(m1, 32);
        float o2 = __shfl_xor(m2, 32);
        int  ocid = __shfl_xor(cid, 32);
        float nm2 = fmaxf(fmaxf(m2, o2), fminf(m1, o1));
        bool take = o1 > m1;
        float nm1 = take ? o1 : m1;
        int  ncid = take ? ocid : cid;

        if (h == 0 && p < N_PTS) {
            out[p] = ncid;
            if (nm1 - nm2 < MARGIN) {                    // too close -> fp64
                int slot = atomicAdd(counter, 1);
                if (slot < capacity) ulist[slot] = p;
            }
        }
    }
}

// ---------------------------------------------------------------- pass 2 ----
// fp64-exact, ONE WAVE PER POINT. Lane q=lane&15 owns one float4 of the dim
// axis; rg=lane>>4 one of 4 rows per load -> each wave-load is a coalesced
// 1 KB read of 4 center rows. dot reduced by shfl_xor butterfly over q bits.
// ||c||^2 comes from the fp64 precompute table.
__launch_bounds__(256)
__global__ void kmeans_pass2(const float* __restrict__ x,
                             const float* __restrict__ centers,
                             const double* __restrict__ m2d,
                             int* __restrict__ out,
                             const int* __restrict__ counter,
                             const int* __restrict__ ulist,
                             int capacity)
{
    int count = *counter;
    if (count > capacity) count = capacity;

    const int tid   = threadIdx.x;
    const int lane  = tid & 63;
    const int q     = lane & 15;                 // float4 chunk of the row
    const int rg    = lane >> 4;                 // row-in-group 0..3
    const int waveg = (blockIdx.x * 256 + tid) >> 6;   // global wave id
    const int nwave = (gridDim.x * 256) >> 6;

    for (int u = waveg; u < count; u += nwave) {
        const int p = ulist[u];
        float4 xv = *(const float4*)(x + (size_t)p * DIM + q * 4);
        const double x0 = xv.x, x1 = xv.y, x2 = xv.z, x3 = xv.w;

        double bv = 1.0e300; int bi = 0;
        #pragma unroll 4
        for (int g = 0; g < 256; ++g) {
            const int row = g * 4 + rg;
            float4 cv = *(const float4*)(centers + (size_t)row * DIM + q * 4);
            double dot = (double)cv.x * x0 + (double)cv.y * x1
                       + (double)cv.z * x2 + (double)cv.w * x3;
            #pragma unroll
            for (int m = 1; m <= 8; m <<= 1)
                dot += __shfl_xor(dot, m);       // all 16 q-lanes get the total
            double s = m2d[row] - 2.0 * dot;
            if (s < bv || (s == bv && row < bi)) { bv = s; bi = row; }
        }
        #pragma unroll
        for (int m = 16; m <= 32; m <<= 1) {     // merge the 4 rg groups
            double ov = __shfl_xor(bv, m);
            int    oi = __shfl_xor(bi, m);
            if (ov < bv || (ov == bv && oi < bi)) { bv = ov; bi = oi; }
        }
        if (lane == 0) out[p] = bi;
    }
}

extern "C" void kernel_launch(void* const* d_in, const int* in_sizes, int n_in,
                              void* d_out, int out_size, void* d_ws, size_t ws_size,
                              hipStream_t stream)
{
    const float* x       = (const float*)d_in[0];
    const float* centers = (const float*)d_in[1];
    int*    out     = (int*)d_out;
    int*    counter = (int*)d_ws;
    double* m2d     = (double*)((char*)d_ws + 1024);
    int*    ulist   = (int*)((char*)d_ws + 1024 + 8192);
    int capacity = (int)((ws_size > 9216 + 64 ? ws_size - 9216 : 0) / sizeof(int));
    if (capacity > N_PTS) capacity = N_PTS;

    hipMemsetAsync(d_ws, 0, 64, stream);
    kmeans_m2pre<<<4, 256, 0, stream>>>(centers, m2d);
    dim3 g1((N_PTS + 255) / 256);     // 1954 blocks x 512 threads, 256 pts each
    kmeans_pass1<<<g1, 512, 0, stream>>>(x, centers, out, counter, ulist, capacity);
    kmeans_pass2<<<1024, 256, 0, stream>>>(x, centers, m2d, out, counter, ulist, capacity);
}